// Round 8
// baseline (176.539 us; speedup 1.0000x reference)
//
#include <hip/hip_runtime.h>

#define IN_F 64
#define HID_F 128
#define CAP 64      // max in-degree slots per node (Poisson(16): P(>64) ~ 1e-20)
#define CHUNK 2048  // edges per partition block (8 reg-cached per thread)
#define CAPB32 1024 // dst-bucket (32-node) buffer capacity (avg ~512, >20 sigma)
#define MAXB32 2048 // >= NB32 = ceil(N/32)  (N <= 65536 by u16 indices)

typedef unsigned short u16;
typedef unsigned int u32;
typedef _Float16 f16;
typedef __attribute__((ext_vector_type(4))) _Float16 f16x4;
typedef __attribute__((ext_vector_type(8))) _Float16 f16x8;
typedef __attribute__((ext_vector_type(8))) u16 u16x8;
typedef __attribute__((ext_vector_type(4))) float f32x4;

// ---------------------------------------------------------------------------
// K1: partition edges into 32-node dst buckets. LDS histogram -> per-block
// global reservation (skipping empty buckets) -> scattered stores. Out-degree
// goes straight to a global L2-resident histogram (fire-and-forget atomics) —
// the whole bufS side-channel is gone. CHUNK=2048 -> 392 blocks (all CUs busy
// vs 98 at CHUNK=8192). Last block: W transpose + sentinel rows.
// ---------------------------------------------------------------------------
__global__ __launch_bounds__(256)
void partition_kernel(const int* __restrict__ src, const int* __restrict__ dst,
                      int* __restrict__ gcurD, int* __restrict__ deg_out,
                      u32* __restrict__ bufD,
                      const float* __restrict__ W1, const float* __restrict__ W2,
                      f16* __restrict__ W1t, f16* __restrict__ W2t,
                      f16* __restrict__ scaled_x, f16* __restrict__ g2,
                      int E, int NB32, int N) {
    if (blockIdx.x == gridDim.x - 1) {
        for (int t = threadIdx.x; t < 2 * IN_F * HID_F; t += 256) {
            if (t < IN_F * HID_F) {
                int n = t / IN_F, k = t % IN_F;
                W1t[t] = (f16)W1[k * HID_F + n];
            } else {
                int i = t - IN_F * HID_F;
                int n = i / HID_F, k = i % HID_F;
                W2t[i] = (f16)W2[k * IN_F + n];
            }
        }
        // zero sentinel rows (padded gathers read row N -> +0.0f)
        for (int t = threadIdx.x; t < IN_F; t += 256) {
            scaled_x[(size_t)N * IN_F + t] = (f16)0.f;
            g2[(size_t)N * IN_F + t]       = (f16)0.f;
        }
        return;
    }
    __shared__ int histD[MAXB32], baseD[MAXB32];
    const int t  = threadIdx.x;
    const int e0 = blockIdx.x * CHUNK;
    const int n  = min(CHUNK, E - e0);

    int ed[8];

    for (int b = t; b < NB32; b += 256) histD[b] = 0;
    __syncthreads();
#pragma unroll
    for (int j = 0; j < 8; ++j) {
        int i = t + j * 256;
        if (i < n) {
            ed[j] = dst[e0 + i];
            atomicAdd(&histD[ed[j] >> 5], 1);
            atomicAdd(&deg_out[src[e0 + i]], 1);   // L2-resident, fire-and-forget
        }
    }
    __syncthreads();
    for (int b = t; b < NB32; b += 256) {
        int h = histD[b];
        if (h) baseD[b] = atomicAdd(&gcurD[b], h);
        histD[b] = 0;  // reuse as running cursor
    }
    __syncthreads();
#pragma unroll
    for (int j = 0; j < 8; ++j) {
        int i = t + j * 256;
        if (i < n) {
            int d  = ed[j];
            int s  = src[e0 + i];   // L1/L2-hot second read (regs freed for MLP)
            int bD = d >> 5;
            int p  = baseD[bD] + atomicAdd(&histD[bD], 1);
            if (p < CAPB32)
                bufD[(size_t)bD * CAPB32 + p] = (u32)s | ((u32)(d & 31) << 16);
        }
    }
}

// ---------------------------------------------------------------------------
// K2 [R3-verified form]: pure streaming — norm_src + fp16 prescale
// (scaled_x = (f16)(x * rsqrt(max(deg_out,1)))). No histogram, no LDS.
// ---------------------------------------------------------------------------
__global__ __launch_bounds__(256)
void srcprep_kernel(const int* __restrict__ deg_out, float* __restrict__ norm_src,
                    const float* __restrict__ x, f16x8* __restrict__ scaled_x,
                    int N) {
    const int tg = blockIdx.x * 256 + threadIdx.x;
    const int node = tg >> 3;
    const int c = tg & 7;
    if (node >= N) return;
    float nsv = rsqrtf((float)max(deg_out[node], 1));
    if (c == 0) norm_src[node] = nsv;
    float4 a = ((const float4*)x)[(size_t)node * 16 + c * 2];
    float4 b = ((const float4*)x)[(size_t)node * 16 + c * 2 + 1];
    f16x8 h;
    h[0] = (f16)(a.x * nsv); h[1] = (f16)(a.y * nsv);
    h[2] = (f16)(a.z * nsv); h[3] = (f16)(a.w * nsv);
    h[4] = (f16)(b.x * nsv); h[5] = (f16)(b.y * nsv);
    h[6] = (f16)(b.z * nsv); h[7] = (f16)(b.w * nsv);
    scaled_x[(size_t)node * 8 + c] = h;
}

// ---------------------------------------------------------------------------
// K3 [R7-verified]: one 32-node dst bucket per block. Phase A: sentinel-
// prefill sl, rebuild slot lists in LDS from bufD, dump padded lists + raw
// degrees to global (K4 consumes -> rebuild paid once). Phase B: 16-deep
// batched gather + double MFMA GEMM.
// ---------------------------------------------------------------------------
__global__ __launch_bounds__(256)
void gather_gemm_kernel(const u32* __restrict__ bufD, const int* __restrict__ gcurD,
                        const f16x8* __restrict__ xs,
                        const f16* __restrict__ W1t, const float* __restrict__ b1,
                        const float* __restrict__ ns,
                        const f16* __restrict__ W2t, f16* __restrict__ g2,
                        u16* __restrict__ slots_g, int* __restrict__ deg_g, int N) {
    constexpr int LDX = IN_F + 8;    // 72 f16 = 144 B row stride
    constexpr int LDH = HID_F + 8;   // 136 f16 = 272 B
    __shared__ __align__(16) u16 sl[32 * CAP];   // 4 KB slot lists
    __shared__ int lcur[32];
    __shared__ float snd[32];
    __shared__ __align__(16) f16 sx[32 * LDX];
    __shared__ __align__(16) f16 h[2][16 * LDH];

    const int t  = threadIdx.x;
    const int b  = blockIdx.x;
    const int r0 = b * 32;

    // ---- phase A: sentinel prefill + LDS slot build ----
    {
        u16x8 sv;
#pragma unroll
        for (int k = 0; k < 8; ++k) sv[k] = (u16)N;
        ((u16x8*)sl)[t] = sv;              // 256 chunks = full 4 KB
    }
    if (t < 32) lcur[t] = 0;
    __syncthreads();
    const int cnt = min(gcurD[b], CAPB32);
    const u32* p = bufD + (size_t)b * CAPB32;
    for (int i = t; i < cnt; i += 256) {
        u32 v = p[i];
        int din = (int)(v >> 16);
        int pos = atomicAdd(&lcur[din], 1);
        if (pos < CAP) sl[din * CAP + pos] = (u16)(v & 0xFFFFu);
    }
    __syncthreads();
    if (t < 32) {
        snd[t] = rsqrtf((float)max(lcur[t], 1));
        if (r0 + t < N) deg_g[r0 + t] = lcur[t];   // raw count (norm semantics)
    }
    __syncthreads();

    // dump padded slot lists for K4 (coalesced, fire-and-forget during gather)
    ((u16x8*)slots_g)[(size_t)b * 256 + t] = ((const u16x8*)sl)[t];

    // ---- phase B: gather, 16-deep batches [R5] ----
    const int row = t >> 3;          // 0..31
    const int c   = t & 7;           // f16x8 chunk
    float acc[8];
#pragma unroll
    for (int k = 0; k < 8; ++k) acc[k] = 0.f;
    {
        int degR = (min(lcur[row], CAP) + 15) & ~15;
        for (int i = 0; i < degR; i += 16) {
            u16x8 sa = *(const u16x8*)(sl + row * CAP + i);
            u16x8 sb = *(const u16x8*)(sl + row * CAP + i + 8);
            f16x8 v[16];
#pragma unroll
            for (int j = 0; j < 8; ++j) v[j]     = xs[(size_t)sa[j] * 8 + c];
#pragma unroll
            for (int j = 0; j < 8; ++j) v[8 + j] = xs[(size_t)sb[j] * 8 + c];
#pragma unroll
            for (int j = 0; j < 16; ++j)
#pragma unroll
                for (int k = 0; k < 8; ++k) acc[k] += (float)v[j][k];
        }
    }
    {   // stash to LDS tile
        f16x8 hv;
#pragma unroll
        for (int k = 0; k < 8; ++k) hv[k] = (f16)acc[k];
        *(f16x8*)&sx[row * LDX + c * 8] = hv;
    }
    __syncthreads();

    const int wave = t >> 6;
    const int lane = t & 63;
    const int nl   = lane & 15;
    const int quad = lane >> 4;

    // ---- stage 1: per sub-tile rt, wave w -> h cols ct = {2w, 2w+1} ----
#pragma unroll
    for (int rt = 0; rt < 2; ++rt) {
        f16x8 a1[2];
#pragma unroll
        for (int kf = 0; kf < 2; ++kf)
            a1[kf] = *(const f16x8*)(sx + (rt * 16 + nl) * LDX + kf * 32 + quad * 8);

        float rs1[4];
#pragma unroll
        for (int reg = 0; reg < 4; ++reg)
            rs1[reg] = snd[rt * 16 + quad * 4 + reg];

        f16* hb = h[rt];
#pragma unroll
        for (int cti = 0; cti < 2; ++cti) {
            const int ct = wave * 2 + cti;
            f32x4 acc1 = (f32x4){0.f, 0.f, 0.f, 0.f};
#pragma unroll
            for (int kf = 0; kf < 2; ++kf) {
                f16x8 bf = *(const f16x8*)(W1t + (ct * 16 + nl) * IN_F + kf * 32 + quad * 8);
                acc1 = __builtin_amdgcn_mfma_f32_16x16x32_f16(a1[kf], bf, acc1, 0, 0, 0);
            }
            float bb = b1[ct * 16 + nl];
#pragma unroll
            for (int reg = 0; reg < 4; ++reg) {
                float v = fmaxf(acc1[reg] * rs1[reg] + bb, 0.f);
                hb[(quad * 4 + reg) * LDH + ct * 16 + nl] = (f16)v;
            }
        }
    }
    __syncthreads();

    // ---- stage 2: per sub-tile rt, wave w -> g2 cols ct = w, K = 128 ----
#pragma unroll
    for (int rt = 0; rt < 2; ++rt) {
        f32x4 acc2 = (f32x4){0.f, 0.f, 0.f, 0.f};
#pragma unroll
        for (int kf = 0; kf < 4; ++kf) {
            f16x8 a2 = *(const f16x8*)(h[rt] + nl * LDH + kf * 32 + quad * 8);
            f16x8 bf = *(const f16x8*)(W2t + (wave * 16 + nl) * HID_F + kf * 32 + quad * 8);
            acc2 = __builtin_amdgcn_mfma_f32_16x16x32_f16(a2, bf, acc2, 0, 0, 0);
        }

        float rs2[4];
#pragma unroll
        for (int reg = 0; reg < 4; ++reg)
            rs2[reg] = ns[min(r0 + rt * 16 + quad * 4 + reg, N - 1)];
#pragma unroll
        for (int reg = 0; reg < 4; ++reg) {
            int r = r0 + rt * 16 + quad * 4 + reg;
            if (r < N)
                g2[(size_t)r * IN_F + wave * 16 + nl] = (f16)(acc2[reg] * rs2[reg]);
        }
    }
}

// ---------------------------------------------------------------------------
// K4 [R7-verified]: flat gather of g2 over the padded global slot lists
// built by K3 (no bufD read, no rebuild, zero LDS -> max occupancy):
//   out[n,:] = agg * rsqrt(max(deg,1)) + b2   (fp32, float4 stores)
// ---------------------------------------------------------------------------
__global__ __launch_bounds__(256)
void gather_out_kernel(const f16x8* __restrict__ xs, const u16* __restrict__ slots_g,
                       const int* __restrict__ deg_g, const float* __restrict__ bias,
                       float4* __restrict__ out, int N) {
    int tg = blockIdx.x * blockDim.x + threadIdx.x;
    int node = tg >> 3;
    int c = tg & 7;
    if (node >= N) return;
    int deg  = deg_g[node];
    int degR = (min(deg, CAP) + 15) & ~15;
    const u16* srow = slots_g + (size_t)node * CAP;
    float acc[8];
#pragma unroll
    for (int k = 0; k < 8; ++k) acc[k] = 0.f;

    for (int i = 0; i < degR; i += 16) {
        u16x8 sa = *(const u16x8*)(srow + i);
        u16x8 sb = *(const u16x8*)(srow + i + 8);
        f16x8 v[16];
#pragma unroll
        for (int j = 0; j < 8; ++j) v[j]     = xs[(size_t)sa[j] * 8 + c];
#pragma unroll
        for (int j = 0; j < 8; ++j) v[8 + j] = xs[(size_t)sb[j] * 8 + c];
#pragma unroll
        for (int j = 0; j < 16; ++j)
#pragma unroll
            for (int k = 0; k < 8; ++k) acc[k] += (float)v[j][k];
    }
    float d = rsqrtf((float)max(deg, 1));
    float4 b0 = ((const float4*)bias)[c * 2];
    float4 b1v = ((const float4*)bias)[c * 2 + 1];
    float4 o0, o1;
    o0.x = acc[0] * d + b0.x;  o0.y = acc[1] * d + b0.y;
    o0.z = acc[2] * d + b0.z;  o0.w = acc[3] * d + b0.w;
    o1.x = acc[4] * d + b1v.x; o1.y = acc[5] * d + b1v.y;
    o1.z = acc[6] * d + b1v.z; o1.w = acc[7] * d + b1v.w;
    out[(size_t)node * 16 + c * 2]     = o0;
    out[(size_t)node * 16 + c * 2 + 1] = o1;
}

extern "C" void kernel_launch(void* const* d_in, const int* in_sizes, int n_in,
                              void* d_out, int out_size, void* d_ws, size_t ws_size,
                              hipStream_t stream) {
    const float* in_feat = (const float*)d_in[0];
    const float* W1      = (const float*)d_in[1];
    const float* b1      = (const float*)d_in[2];
    const float* W2      = (const float*)d_in[3];
    const float* b2      = (const float*)d_in[4];
    const int*   src     = (const int*)d_in[5];
    const int*   dst     = (const int*)d_in[6];

    const int N = in_sizes[0] / IN_F;
    const int E = in_sizes[5];
    float* out = (float*)d_out;

    const int NB32 = (N + 31) >> 5;    // 1563 for N=50000

    // workspace (~32 MB):
    // ints: gcurD[MAXB32] | deg_out[N] | deg_g[N]
    // f32:  norm_src[N]
    // f16:  scaled_x[(N+1)*64] | g2[(N+1)*64] | W1t[8192] | W2t[8192]
    // u32:  bufD[MAXB32*CAPB32] ; u16: slots_g[N*CAP]
    int* gcurD      = (int*)d_ws;
    int* deg_out    = gcurD + MAXB32;
    int* deg_g      = deg_out + N;
    float* norm_src = (float*)(deg_g + N);
    f16* scaled_x   = (f16*)(norm_src + N);
    f16* g2         = scaled_x + (size_t)(N + 1) * IN_F;
    f16* W1t        = g2 + (size_t)(N + 1) * IN_F;
    f16* W2t        = W1t + IN_F * HID_F;
    u32* bufD       = (u32*)(W2t + IN_F * HID_F);
    u16* slots_g    = (u16*)(bufD + (size_t)MAXB32 * CAPB32);

    // ---- 1: bucket partition + global out-degree + W prep + sentinels ----
    hipMemsetAsync(gcurD, 0, sizeof(int) * (MAXB32 + N), stream);
    partition_kernel<<<(E + CHUNK - 1) / CHUNK + 1, 256, 0, stream>>>(
        src, dst, gcurD, deg_out, bufD, W1, W2, W1t, W2t,
        scaled_x, g2, E, NB32, N);

    // ---- 2: src norms + fp16 prescale (pure streaming) ----
    srcprep_kernel<<<(N * 8 + 255) / 256, 256, 0, stream>>>(
        deg_out, norm_src, in_feat, (f16x8*)scaled_x, N);

    // ---- 3: LDS slot build (+dump for K4) + gather + double MFMA GEMM ----
    gather_gemm_kernel<<<NB32, 256, 0, stream>>>(
        bufD, gcurD, (const f16x8*)scaled_x, W1t, b1, norm_src, W2t, g2,
        slots_g, deg_g, N);

    // ---- 4: flat gather g2 over dumped slots -> (*nd + b2) -> fp32 out ----
    gather_out_kernel<<<(N * 8 + 255) / 256, 256, 0, stream>>>(
        (const f16x8*)g2, slots_g, deg_g, b2, (float4*)out, N);
}

// Round 9
// 150.263 us; speedup vs baseline: 1.1749x; 1.1749x over previous
//
#include <hip/hip_runtime.h>

#define IN_F 64
#define HID_F 128
#define CAP 64      // max in-degree slots per node (Poisson(16): P(>64) ~ 1e-20)
#define CHUNK 8192  // edges per partition block (32 reg-cached per thread)
            // NOTE R8 lesson: CHUNK/NB32 >= ~5 edges/bucket/block needed for
            // bufD scatter-store line amortization (CHUNK=2048 -> 11x write-amp)
#define CAPB 4096   // src-bucket (128-node) buffer capacity (avg ~2046, >40 sigma)
#define MAXB 512    // >= NBS = ceil(N/128)
#define CAPB32 1024 // dst-bucket (32-node) buffer capacity (avg ~512, >20 sigma)
#define MAXB32 2048 // >= NB32 = ceil(N/32)  (N <= 65536 by u16 indices)

typedef unsigned short u16;
typedef unsigned int u32;
typedef _Float16 f16;
typedef __attribute__((ext_vector_type(4))) _Float16 f16x4;
typedef __attribute__((ext_vector_type(8))) _Float16 f16x8;
typedef __attribute__((ext_vector_type(8))) u16 u16x8;
typedef __attribute__((ext_vector_type(4))) float f32x4;

// ---------------------------------------------------------------------------
// K1 [R7-verified, CHUNK=8192]: partition edges into per-bucket regions. LDS
// histogram -> per-block global reservation -> scattered stores. Edges
// register-cached (single global read, 32/thread compile-time-indexed).
// Last block: W1/W2 -> transposed fp16 + zero sentinel payload rows (index N).
// ---------------------------------------------------------------------------
__global__ __launch_bounds__(256)
void partition_kernel(const int* __restrict__ src, const int* __restrict__ dst,
                      int* __restrict__ gcurD, int* __restrict__ gcurS,
                      u32* __restrict__ bufD, u16* __restrict__ bufS,
                      const float* __restrict__ W1, const float* __restrict__ W2,
                      f16* __restrict__ W1t, f16* __restrict__ W2t,
                      f16* __restrict__ scaled_x, f16* __restrict__ g2,
                      int E, int NB32, int NBS, int N) {
    if (blockIdx.x == gridDim.x - 1) {
        for (int t = threadIdx.x; t < 2 * IN_F * HID_F; t += 256) {
            if (t < IN_F * HID_F) {
                int n = t / IN_F, k = t % IN_F;
                W1t[t] = (f16)W1[k * HID_F + n];
            } else {
                int i = t - IN_F * HID_F;
                int n = i / HID_F, k = i % HID_F;
                W2t[i] = (f16)W2[k * IN_F + n];
            }
        }
        // zero sentinel rows (padded gathers read row N -> +0.0f)
        for (int t = threadIdx.x; t < IN_F; t += 256) {
            scaled_x[(size_t)N * IN_F + t] = (f16)0.f;
            g2[(size_t)N * IN_F + t]       = (f16)0.f;
        }
        return;
    }
    __shared__ int histD[MAXB32], baseD[MAXB32], histS[MAXB], baseS[MAXB];
    const int t  = threadIdx.x;
    const int e0 = blockIdx.x * CHUNK;
    const int n  = min(CHUNK, E - e0);

    int ed[32], es[32];

    for (int b = t; b < NB32; b += 256) histD[b] = 0;
    for (int b = t; b < NBS;  b += 256) histS[b] = 0;
    __syncthreads();
#pragma unroll
    for (int j = 0; j < 32; ++j) {
        int i = t + j * 256;
        if (i < n) {
            ed[j] = dst[e0 + i];
            es[j] = src[e0 + i];
            atomicAdd(&histD[ed[j] >> 5], 1);
            atomicAdd(&histS[es[j] >> 7], 1);
        }
    }
    __syncthreads();
    for (int b = t; b < NB32; b += 256) {
        baseD[b] = atomicAdd(&gcurD[b], histD[b]);
        histD[b] = 0;  // reuse as running cursor
    }
    for (int b = t; b < NBS; b += 256) {
        baseS[b] = atomicAdd(&gcurS[b], histS[b]);
        histS[b] = 0;
    }
    __syncthreads();
#pragma unroll
    for (int j = 0; j < 32; ++j) {
        int i = t + j * 256;
        if (i < n) {
            int d  = ed[j];
            int s  = es[j];
            int bD = d >> 5, bS = s >> 7;
            int p  = baseD[bD] + atomicAdd(&histD[bD], 1);
            if (p < CAPB32)
                bufD[(size_t)bD * CAPB32 + p] = (u32)s | ((u32)(d & 31) << 16);
            int p2 = baseS[bS] + atomicAdd(&histS[bS], 1);
            if (p2 < CAPB) bufS[(size_t)bS * CAPB + p2] = (u16)s;
        }
    }
}

// ---------------------------------------------------------------------------
// K2 [R5-verified]: per 128-node src bucket: out-degree histogram ->
// norm_src + fp16 prescale (scaled_x = (f16)(x * ns)).
// ---------------------------------------------------------------------------
__global__ __launch_bounds__(256)
void srcprep_kernel(const u16* __restrict__ bufS, const int* __restrict__ gcurS,
                    float* __restrict__ norm_src,
                    const float* __restrict__ x, f16x4* __restrict__ scaled_x,
                    int N) {
    __shared__ int lcur[128];
    const int t = threadIdx.x;
    if (t < 128) lcur[t] = 0;
    __syncthreads();
    const int b = blockIdx.x;
    const int cnt = min(gcurS[b], CAPB);
    const u16* p = bufS + (size_t)b * CAPB;
    for (int i = t; i < cnt; i += 256)
        atomicAdd(&lcur[p[i] & 127], 1);
    __syncthreads();
    const int node0 = b * 128;
    if (t < 128 && node0 + t < N)
        norm_src[node0 + t] = rsqrtf((float)max(lcur[t], 1));
    for (int i = t; i < 128 * 16; i += 256) {
        int r = i >> 4, c = i & 15;
        int node = node0 + r;
        if (node < N) {
            float ns = rsqrtf((float)max(lcur[r], 1));
            float4 v = ((const float4*)x)[(size_t)node * 16 + c];
            f16x4 h;
            h.x = (f16)(v.x * ns); h.y = (f16)(v.y * ns);
            h.z = (f16)(v.z * ns); h.w = (f16)(v.w * ns);
            scaled_x[(size_t)node * 16 + c] = h;
        }
    }
}

// ---------------------------------------------------------------------------
// K3 [R7-verified]: one 32-node dst bucket per block. Phase A: sentinel-
// prefill sl, rebuild slot lists in LDS from bufD, dump padded lists + raw
// degrees to global (K4 consumes -> rebuild paid once). Phase B: 16-deep
// batched gather + double MFMA GEMM.
// ---------------------------------------------------------------------------
__global__ __launch_bounds__(256)
void gather_gemm_kernel(const u32* __restrict__ bufD, const int* __restrict__ gcurD,
                        const f16x8* __restrict__ xs,
                        const f16* __restrict__ W1t, const float* __restrict__ b1,
                        const float* __restrict__ ns,
                        const f16* __restrict__ W2t, f16* __restrict__ g2,
                        u16* __restrict__ slots_g, int* __restrict__ deg_g, int N) {
    constexpr int LDX = IN_F + 8;    // 72 f16 = 144 B row stride
    constexpr int LDH = HID_F + 8;   // 136 f16 = 272 B
    __shared__ __align__(16) u16 sl[32 * CAP];   // 4 KB slot lists
    __shared__ int lcur[32];
    __shared__ float snd[32];
    __shared__ __align__(16) f16 sx[32 * LDX];
    __shared__ __align__(16) f16 h[2][16 * LDH];

    const int t  = threadIdx.x;
    const int b  = blockIdx.x;
    const int r0 = b * 32;

    // ---- phase A: sentinel prefill + LDS slot build ----
    {
        u16x8 sv;
#pragma unroll
        for (int k = 0; k < 8; ++k) sv[k] = (u16)N;
        ((u16x8*)sl)[t] = sv;              // 256 chunks = full 4 KB
    }
    if (t < 32) lcur[t] = 0;
    __syncthreads();
    const int cnt = min(gcurD[b], CAPB32);
    const u32* p = bufD + (size_t)b * CAPB32;
    for (int i = t; i < cnt; i += 256) {
        u32 v = p[i];
        int din = (int)(v >> 16);
        int pos = atomicAdd(&lcur[din], 1);
        if (pos < CAP) sl[din * CAP + pos] = (u16)(v & 0xFFFFu);
    }
    __syncthreads();
    if (t < 32) {
        snd[t] = rsqrtf((float)max(lcur[t], 1));
        if (r0 + t < N) deg_g[r0 + t] = lcur[t];   // raw count (norm semantics)
    }
    __syncthreads();

    // dump padded slot lists for K4 (coalesced, fire-and-forget during gather)
    ((u16x8*)slots_g)[(size_t)b * 256 + t] = ((const u16x8*)sl)[t];

    // ---- phase B: gather, 16-deep batches [R5] ----
    const int row = t >> 3;          // 0..31
    const int c   = t & 7;           // f16x8 chunk
    float acc[8];
#pragma unroll
    for (int k = 0; k < 8; ++k) acc[k] = 0.f;
    {
        int degR = (min(lcur[row], CAP) + 15) & ~15;
        for (int i = 0; i < degR; i += 16) {
            u16x8 sa = *(const u16x8*)(sl + row * CAP + i);
            u16x8 sb = *(const u16x8*)(sl + row * CAP + i + 8);
            f16x8 v[16];
#pragma unroll
            for (int j = 0; j < 8; ++j) v[j]     = xs[(size_t)sa[j] * 8 + c];
#pragma unroll
            for (int j = 0; j < 8; ++j) v[8 + j] = xs[(size_t)sb[j] * 8 + c];
#pragma unroll
            for (int j = 0; j < 16; ++j)
#pragma unroll
                for (int k = 0; k < 8; ++k) acc[k] += (float)v[j][k];
        }
    }
    {   // stash to LDS tile
        f16x8 hv;
#pragma unroll
        for (int k = 0; k < 8; ++k) hv[k] = (f16)acc[k];
        *(f16x8*)&sx[row * LDX + c * 8] = hv;
    }
    __syncthreads();

    const int wave = t >> 6;
    const int lane = t & 63;
    const int nl   = lane & 15;
    const int quad = lane >> 4;

    // ---- stage 1: per sub-tile rt, wave w -> h cols ct = {2w, 2w+1} ----
#pragma unroll
    for (int rt = 0; rt < 2; ++rt) {
        f16x8 a1[2];
#pragma unroll
        for (int kf = 0; kf < 2; ++kf)
            a1[kf] = *(const f16x8*)(sx + (rt * 16 + nl) * LDX + kf * 32 + quad * 8);

        float rs1[4];
#pragma unroll
        for (int reg = 0; reg < 4; ++reg)
            rs1[reg] = snd[rt * 16 + quad * 4 + reg];

        f16* hb = h[rt];
#pragma unroll
        for (int cti = 0; cti < 2; ++cti) {
            const int ct = wave * 2 + cti;
            f32x4 acc1 = (f32x4){0.f, 0.f, 0.f, 0.f};
#pragma unroll
            for (int kf = 0; kf < 2; ++kf) {
                f16x8 bf = *(const f16x8*)(W1t + (ct * 16 + nl) * IN_F + kf * 32 + quad * 8);
                acc1 = __builtin_amdgcn_mfma_f32_16x16x32_f16(a1[kf], bf, acc1, 0, 0, 0);
            }
            float bb = b1[ct * 16 + nl];
#pragma unroll
            for (int reg = 0; reg < 4; ++reg) {
                float v = fmaxf(acc1[reg] * rs1[reg] + bb, 0.f);
                hb[(quad * 4 + reg) * LDH + ct * 16 + nl] = (f16)v;
            }
        }
    }
    __syncthreads();

    // ---- stage 2: per sub-tile rt, wave w -> g2 cols ct = w, K = 128 ----
#pragma unroll
    for (int rt = 0; rt < 2; ++rt) {
        f32x4 acc2 = (f32x4){0.f, 0.f, 0.f, 0.f};
#pragma unroll
        for (int kf = 0; kf < 4; ++kf) {
            f16x8 a2 = *(const f16x8*)(h[rt] + nl * LDH + kf * 32 + quad * 8);
            f16x8 bf = *(const f16x8*)(W2t + (wave * 16 + nl) * HID_F + kf * 32 + quad * 8);
            acc2 = __builtin_amdgcn_mfma_f32_16x16x32_f16(a2, bf, acc2, 0, 0, 0);
        }

        float rs2[4];
#pragma unroll
        for (int reg = 0; reg < 4; ++reg)
            rs2[reg] = ns[min(r0 + rt * 16 + quad * 4 + reg, N - 1)];
#pragma unroll
        for (int reg = 0; reg < 4; ++reg) {
            int r = r0 + rt * 16 + quad * 4 + reg;
            if (r < N)
                g2[(size_t)r * IN_F + wave * 16 + nl] = (f16)(acc2[reg] * rs2[reg]);
        }
    }
}

// ---------------------------------------------------------------------------
// K4 [R7-verified]: flat gather of g2 over the padded global slot lists
// built by K3 (no bufD read, no rebuild, zero LDS -> max occupancy):
//   out[n,:] = agg * rsqrt(max(deg,1)) + b2   (fp32, float4 stores)
// ---------------------------------------------------------------------------
__global__ __launch_bounds__(256)
void gather_out_kernel(const f16x8* __restrict__ xs, const u16* __restrict__ slots_g,
                       const int* __restrict__ deg_g, const float* __restrict__ bias,
                       float4* __restrict__ out, int N) {
    int tg = blockIdx.x * blockDim.x + threadIdx.x;
    int node = tg >> 3;
    int c = tg & 7;
    if (node >= N) return;
    int deg  = deg_g[node];
    int degR = (min(deg, CAP) + 15) & ~15;
    const u16* srow = slots_g + (size_t)node * CAP;
    float acc[8];
#pragma unroll
    for (int k = 0; k < 8; ++k) acc[k] = 0.f;

    for (int i = 0; i < degR; i += 16) {
        u16x8 sa = *(const u16x8*)(srow + i);
        u16x8 sb = *(const u16x8*)(srow + i + 8);
        f16x8 v[16];
#pragma unroll
        for (int j = 0; j < 8; ++j) v[j]     = xs[(size_t)sa[j] * 8 + c];
#pragma unroll
        for (int j = 0; j < 8; ++j) v[8 + j] = xs[(size_t)sb[j] * 8 + c];
#pragma unroll
        for (int j = 0; j < 16; ++j)
#pragma unroll
            for (int k = 0; k < 8; ++k) acc[k] += (float)v[j][k];
    }
    float d = rsqrtf((float)max(deg, 1));
    float4 b0 = ((const float4*)bias)[c * 2];
    float4 b1v = ((const float4*)bias)[c * 2 + 1];
    float4 o0, o1;
    o0.x = acc[0] * d + b0.x;  o0.y = acc[1] * d + b0.y;
    o0.z = acc[2] * d + b0.z;  o0.w = acc[3] * d + b0.w;
    o1.x = acc[4] * d + b1v.x; o1.y = acc[5] * d + b1v.y;
    o1.z = acc[6] * d + b1v.z; o1.w = acc[7] * d + b1v.w;
    out[(size_t)node * 16 + c * 2]     = o0;
    out[(size_t)node * 16 + c * 2 + 1] = o1;
}

extern "C" void kernel_launch(void* const* d_in, const int* in_sizes, int n_in,
                              void* d_out, int out_size, void* d_ws, size_t ws_size,
                              hipStream_t stream) {
    const float* in_feat = (const float*)d_in[0];
    const float* W1      = (const float*)d_in[1];
    const float* b1      = (const float*)d_in[2];
    const float* W2      = (const float*)d_in[3];
    const float* b2      = (const float*)d_in[4];
    const int*   src     = (const int*)d_in[5];
    const int*   dst     = (const int*)d_in[6];

    const int N = in_sizes[0] / IN_F;
    const int E = in_sizes[5];
    float* out = (float*)d_out;

    const int NB32 = (N + 31) >> 5;    // 1563 for N=50000
    const int NBS  = (N + 127) >> 7;   // 391

    // workspace (~33 MB):
    // ints: gcurD[MAXB32] | gcurS[MAXB] | deg_g[N]
    // f32:  norm_src[N]
    // f16:  scaled_x[(N+1)*64] | g2[(N+1)*64] | W1t[8192] | W2t[8192]
    // u32:  bufD[MAXB32*CAPB32] ; u16: slots_g[N*CAP] | bufS[MAXB*CAPB]
    int* gcurD      = (int*)d_ws;
    int* gcurS      = gcurD + MAXB32;
    int* deg_g      = gcurS + MAXB;
    float* norm_src = (float*)(deg_g + N);
    f16* scaled_x   = (f16*)(norm_src + N);
    f16* g2         = scaled_x + (size_t)(N + 1) * IN_F;
    f16* W1t        = g2 + (size_t)(N + 1) * IN_F;
    f16* W2t        = W1t + IN_F * HID_F;
    u32* bufD       = (u32*)(W2t + IN_F * HID_F);
    u16* slots_g    = (u16*)(bufD + (size_t)MAXB32 * CAPB32);
    u16* bufS       = slots_g + (size_t)N * CAP;

    // ---- 1: bucket partition (32-node dst buckets) + W prep + sentinels ----
    hipMemsetAsync(gcurD, 0, sizeof(int) * (MAXB32 + MAXB), stream);
    partition_kernel<<<(E + CHUNK - 1) / CHUNK + 1, 256, 0, stream>>>(
        src, dst, gcurD, gcurS, bufD, bufS, W1, W2, W1t, W2t,
        scaled_x, g2, E, NB32, NBS, N);

    // ---- 2: src norms + fp16 prescale ----
    srcprep_kernel<<<NBS, 256, 0, stream>>>(
        bufS, gcurS, norm_src, in_feat, (f16x4*)scaled_x, N);

    // ---- 3: LDS slot build (+dump for K4) + gather + double MFMA GEMM ----
    gather_gemm_kernel<<<NB32, 256, 0, stream>>>(
        bufD, gcurD, (const f16x8*)scaled_x, W1t, b1, norm_src, W2t, g2,
        slots_g, deg_g, N);

    // ---- 4: flat gather g2 over dumped slots -> (*nd + b2) -> fp32 out ----
    gather_out_kernel<<<(N * 8 + 255) / 256, 256, 0, stream>>>(
        (const f16x8*)g2, slots_g, deg_g, b2, (float4*)out, N);
}